// Round 8
// baseline (149.958 us; speedup 1.0000x reference)
//
#include <hip/hip_runtime.h>
#include <hip/hip_bf16.h>

// Problem constants
#define SQn 2048
#define SKn 2048
#define DMn 1024
#define NHn 16
#define DHn 64

typedef __attribute__((ext_vector_type(8))) short bf16x8;
typedef __attribute__((ext_vector_type(4))) float f32x4;

#define QSCALE 0.1803368801f  /* (1/sqrt(64)) / ln2 : folds softmax scale + exp->exp2 */

__device__ __forceinline__ short f2bf(float f) {
  union { float f; unsigned u; } a; a.f = f;
  return (short)((a.u + 0x7FFFu + ((a.u >> 16) & 1u)) >> 16);  // RNE
}

__device__ __forceinline__ unsigned cvt_pk_bf16(float lo, float hi) {
  unsigned r;
  asm("v_cvt_pk_bf16_f32 %0, %1, %2" : "=v"(r) : "v"(lo), "v"(hi));
  return r;
}

__device__ __forceinline__ void gload16(const void* g, void* l) {
  __builtin_amdgcn_global_load_lds(
      (__attribute__((address_space(1))) void*)g,
      (__attribute__((address_space(3))) void*)l, 16, 0, 0);
}

// ---------------- fused f32 -> bf16 cast for Q,K,V (one launch) ----------------
__global__ __launch_bounds__(256) void cast3_f32_bf16(const float* __restrict__ A,
                                                      const float* __restrict__ B,
                                                      const float* __restrict__ C,
                                                      short* __restrict__ out, int n4each) {
  int i = blockIdx.x * 256 + threadIdx.x;
  const float* src;
  int j = i;
  if (i < n4each) src = A;
  else if (i < 2 * n4each) { src = B; j = i - n4each; }
  else { src = C; j = i - 2 * n4each; }
  float4 f = ((const float4*)src)[j];
  short4 o;
  o.x = f2bf(f.x); o.y = f2bf(f.y); o.z = f2bf(f.z); o.w = f2bf(f.w);
  ((short4*)out)[i] = o;
}

// ---------------- W [K][N] f32 -> Wt [N][K] bf16, 4 weights in one launch --------
__global__ __launch_bounds__(256) void transpose_cast4(
    const float* __restrict__ W0, const float* __restrict__ W1,
    const float* __restrict__ W2, const float* __restrict__ W3,
    short* __restrict__ WtBase) {
  const int z = blockIdx.z;
  const float* W = (z == 0) ? W0 : (z == 1) ? W1 : (z == 2) ? W2 : W3;
  short* Wt = WtBase + (size_t)z * DMn * DMn;
  __shared__ float t[32][33];
  int bx = blockIdx.x * 32;  // N range
  int by = blockIdx.y * 32;  // K range
  int tx = threadIdx.x, ty = threadIdx.y;  // 32 x 8
#pragma unroll
  for (int j = 0; j < 4; ++j)
    t[ty + j * 8][tx] = W[(size_t)(by + ty + j * 8) * DMn + bx + tx];
  __syncthreads();
#pragma unroll
  for (int j = 0; j < 4; ++j)
    Wt[(size_t)(bx + ty + j * 8) * DMn + by + tx] = f2bf(t[tx][ty + j * 8]);
}

// ---------------- bf16 GEMM, 2-phase double-buffered (T3 minimum) ---------------
// Projections: z=0 -> q scaled by QSCALE, [b][h][s][64]; z=1 -> k same layout;
//              z=2 -> V^T layout [b][h][d][s].
__global__ __launch_bounds__(256) void gemm_bt3(
    const short* __restrict__ A0, const short* __restrict__ A1, const short* __restrict__ A2,
    const short* __restrict__ B0, const short* __restrict__ B1, const short* __restrict__ B2,
    const float* __restrict__ c0, const float* __restrict__ c1, const float* __restrict__ c2,
    short* __restrict__ O0, short* __restrict__ O1, short* __restrict__ O2) {
  constexpr int K = 1024;
  const int z = blockIdx.z;
  const short* A  = (z == 0) ? A0 : (z == 1) ? A1 : A2;
  const short* Bt = (z == 0) ? B0 : (z == 1) ? B1 : B2;
  const float* bias = (z == 0) ? c0 : (z == 1) ? c1 : c2;
  short* Cout = (z == 0) ? O0 : (z == 1) ? O1 : O2;

  __shared__ short As[2][128 * 32];
  __shared__ short Bs[2][128 * 32];
  const int tid = threadIdx.x;
  const int lane = tid & 63;
  const int wid = tid >> 6;
  const int wr = wid >> 1, wc = wid & 1;
  const int bm = blockIdx.x * 128, bn = blockIdx.y * 128;

  f32x4 acc[4][4] = {};

  const int srow = tid >> 2;
  const int scol = (tid & 3) * 8;
  const short* Ag = A + (size_t)bm * K;
  const short* Bg = Bt + (size_t)bn * K;

#define GSTAGE(buf, k0)                                                        \
  gload16(Ag + (size_t)srow * K + (k0) + scol,        As[buf] + wid * 512);    \
  gload16(Ag + (size_t)(srow + 64) * K + (k0) + scol, As[buf] + 2048 + wid * 512); \
  gload16(Bg + (size_t)srow * K + (k0) + scol,        Bs[buf] + wid * 512);    \
  gload16(Bg + (size_t)(srow + 64) * K + (k0) + scol, Bs[buf] + 2048 + wid * 512);

  GSTAGE(0, 0);
  __syncthreads();

  int cur = 0;
  const int rowA = wr * 64 + (lane & 15);
  const int rowB = wc * 64 + (lane & 15);
  const int ko = (lane >> 4) * 8;
  for (int k0 = 0; k0 < K; k0 += 32) {
    if (k0 + 32 < K) { GSTAGE(cur ^ 1, k0 + 32); }  // flies under this step's MFMA

    bf16x8 a[4], b[4];
#pragma unroll
    for (int m = 0; m < 4; ++m) a[m] = *(const bf16x8*)(As[cur] + (rowA + m * 16) * 32 + ko);
#pragma unroll
    for (int n = 0; n < 4; ++n) b[n] = *(const bf16x8*)(Bs[cur] + (rowB + n * 16) * 32 + ko);
#pragma unroll
    for (int m = 0; m < 4; ++m)
#pragma unroll
      for (int n = 0; n < 4; ++n)
        acc[m][n] = __builtin_amdgcn_mfma_f32_16x16x32_bf16(a[m], b[n], acc[m][n], 0, 0, 0);

    __syncthreads();   // drains stage vmcnt; next tile ready, cur safe to overwrite
    cur ^= 1;
  }
#undef GSTAGE

  // epilogue: C/D layout col=lane&15, row=(lane>>4)*4+i
  const int crow0 = bm + wr * 64 + ((lane >> 4) * 4);
  const int ccol0 = bn + wc * 64 + (lane & 15);
#pragma unroll
  for (int m = 0; m < 4; ++m)
#pragma unroll
    for (int n = 0; n < 4; ++n) {
      int col = ccol0 + n * 16;
      float bv = bias[col];
#pragma unroll
      for (int i = 0; i < 4; ++i) {
        int row = crow0 + m * 16 + i;
        float val = acc[m][n][i] + bv;
        int bb = row >> 11, s = row & 2047;   // SQ=2048
        int hh = col >> 6, d = col & 63;      // DH=64
        if (z == 2) {  // V^T: [b][h][d][s]
          Cout[((((size_t)bb * NHn + hh) * DHn + d) << 11) + s] = f2bf(val);
        } else {
          if (z == 0) val *= QSCALE;          // fold softmax scale into q
          Cout[((((size_t)bb * NHn + hh) * SQn + s) << 6) + d] = f2bf(val);
        }
      }
    }
}

// ---------------- final GEMM, 128x64 tile, 2-phase (512 blocks = 2/CU) ----------
__global__ __launch_bounds__(256) void gemm_n64(const short* __restrict__ A,
                                                const short* __restrict__ Bt,
                                                const float* __restrict__ bias,
                                                float* __restrict__ C) {
  constexpr int K = 1024, N = 1024;
  __shared__ short As[2][128 * 32];
  __shared__ short Bs[2][64 * 32];
  const int tid = threadIdx.x;
  const int lane = tid & 63;
  const int wid = tid >> 6;
  const int wr = wid >> 1, wc = wid & 1;   // waves 2x2, wave tile 64x32
  const int bm = blockIdx.x * 128, bn = blockIdx.y * 64;

  f32x4 acc[4][2] = {};

  const int srow = tid >> 2;
  const int scol = (tid & 3) * 8;
  const short* Ag = A + (size_t)bm * K;
  const short* Bg = Bt + (size_t)bn * K;

#define GSTAGE(buf, k0)                                                        \
  gload16(Ag + (size_t)srow * K + (k0) + scol,        As[buf] + wid * 512);    \
  gload16(Ag + (size_t)(srow + 64) * K + (k0) + scol, As[buf] + 2048 + wid * 512); \
  gload16(Bg + (size_t)srow * K + (k0) + scol,        Bs[buf] + wid * 512);

  GSTAGE(0, 0);
  __syncthreads();

  int cur = 0;
  const int rowA = wr * 64 + (lane & 15);
  const int rowB = wc * 32 + (lane & 15);
  const int ko = (lane >> 4) * 8;
  for (int k0 = 0; k0 < K; k0 += 32) {
    if (k0 + 32 < K) { GSTAGE(cur ^ 1, k0 + 32); }

    bf16x8 a[4], b[2];
#pragma unroll
    for (int m = 0; m < 4; ++m) a[m] = *(const bf16x8*)(As[cur] + (rowA + m * 16) * 32 + ko);
#pragma unroll
    for (int n = 0; n < 2; ++n) b[n] = *(const bf16x8*)(Bs[cur] + (rowB + n * 16) * 32 + ko);
#pragma unroll
    for (int m = 0; m < 4; ++m)
#pragma unroll
      for (int n = 0; n < 2; ++n)
        acc[m][n] = __builtin_amdgcn_mfma_f32_16x16x32_bf16(a[m], b[n], acc[m][n], 0, 0, 0);

    __syncthreads();
    cur ^= 1;
  }
#undef GSTAGE

  const int crow0 = bm + wr * 64 + ((lane >> 4) * 4);
  const int ccol0 = bn + wc * 32 + (lane & 15);
#pragma unroll
  for (int m = 0; m < 4; ++m)
#pragma unroll
    for (int n = 0; n < 2; ++n) {
      int col = ccol0 + n * 16;
      float bv = bias[col];
#pragma unroll
      for (int i = 0; i < 4; ++i) {
        int row = crow0 + m * 16 + i;
        C[(size_t)row * N + col] = acc[m][n][i] + bv;
      }
    }
}

// ---------------- fused masked flash attention ----------------
// Swapped QK^T (lane owns one q row), double-buffered K/V, cvt_pk P-pack,
// shuffle-free fast path: per-lane partial max check (T13 extended), per-lane
// partial lrun reduced once at the end. XCD-aware head placement.
// LDS = 2*8K (K) + 2*8K (V) + 8K (P) = 40960 -> 4 blocks/CU.
__global__ __launch_bounds__(256, 4) void attn(const short* __restrict__ q,
                                               const short* __restrict__ k,
                                               const short* __restrict__ vt,
                                               const int* __restrict__ mask,
                                               short* __restrict__ out) {
  __shared__ short Ks[2][64 * 64];   // [key][d], chunk-swizzled ^(key&7)
  __shared__ short Vs[2][64 * 64];   // [d][key], chunk-swizzled ^(d&7)
  __shared__ short Ps[4][16 * 64];   // per-wave P [16 q][64 key], 8B-slot XOR swizzle

  const int tid = threadIdx.x;
  const int lane = tid & 63;
  const int w = tid >> 6;
  // XCD-aware remap: blocks on one XCD (virt&7 under round-robin dispatch)
  // cover 4 heads -> K/V working set 2MB fits that XCD's 4MB L2.
  const int virt = blockIdx.x;
  const int rest = virt >> 3;
  const int bh = (virt & 7) * 4 + (rest & 3);   // 0..31 = b*16+h
  const int qt = rest >> 2;                     // 0..31
  const int h = bh & 15;
  const int b = bh >> 4;
  const size_t hoff = (size_t)bh * (SQn * DHn);

  const int c_ = lane & 15, g_ = lane >> 4;
  const int swz = (c_ & 7) << 4;         // P-buffer byte swizzle (bits 4-6)

  // Q hoist (B-operand of swapped QK^T)
  bf16x8 qf[2];
  {
    const short* qp = q + hoff + (size_t)(qt * 64 + w * 16 + c_) * DHn + g_ * 8;
    qf[0] = *(const bf16x8*)qp;
    qf[1] = *(const bf16x8*)(qp + 32);
  }

  // staging geometry (loop-invariant per thread)
  const int c0i = tid, c1i = 256 + tid;
  const int r0 = c0i >> 3, gch0 = (c0i & 7) ^ (r0 & 7);
  const int r1 = c1i >> 3, gch1 = (c1i & 7) ^ (r1 & 7);
  const size_t kO0 = (size_t)r0 * DHn + gch0 * 8;
  const size_t kO1 = (size_t)r1 * DHn + gch1 * 8;
  const size_t vO0 = (size_t)r0 * SKn + gch0 * 8;
  const size_t vO1 = (size_t)r1 * SKn + gch1 * 8;
  const int ldsO0 = (w * 64) * 8;
  const int ldsO1 = (256 + w * 64) * 8;

  const int* mrow = mask + (size_t)b * SKn;

  float mrun = -1e30f;   // running max, common across the 4 lanes of a q-row
  float lrun = 0.f;      // PER-LANE partial sum (this lane's key quarter)
  f32x4 o[4] = {};
  char* PwB = (char*)Ps[w];

#define STAGE(buf, kbase, vbase)                    \
  gload16((kbase) + kO0, &Ks[buf][ldsO0]);          \
  gload16((kbase) + kO1, &Ks[buf][ldsO1]);          \
  gload16((vbase) + vO0, &Vs[buf][ldsO0]);          \
  gload16((vbase) + vO1, &Vs[buf][ldsO1]);

  // ---- prologue: stage tile 0 into buf 0, mask tile 0 into regs ----
  const short* kpre = k + hoff;
  const short* vpre = vt + hoff;
  int4 mnext[4];
  STAGE(0, kpre, vpre);
#pragma unroll
  for (int n = 0; n < 4; ++n) mnext[n] = *(const int4*)(mrow + n * 16 + g_ * 4);
  kpre += 64 * DHn;
  vpre += 64;
  const int* mpre = mrow + 64;
  __syncthreads();

  int cur = 0;
  for (int kt = 0; kt < SKn / 64; ++kt) {
    int4 mcur[4];
#pragma unroll
    for (int n = 0; n < 4; ++n) mcur[n] = mnext[n];

    // ---- prefetch tile kt+1 into buf^1 (flies under this tile's compute) ----
    if (kt + 1 < SKn / 64) {
      STAGE(cur ^ 1, kpre, vpre);
#pragma unroll
      for (int n = 0; n < 4; ++n) mnext[n] = *(const int4*)(mpre + n * 16 + g_ * 4);
      kpre += 64 * DHn;
      vpre += 64;
      mpre += 64;
    }

    const short* Kc = Ks[cur];
    const short* Vc = Vs[cur];

    // ---- S^T = K Q^T : lane holds S[q=c_][key = 16n + 4g_ + i] ----
    f32x4 s[4];
    __builtin_amdgcn_s_setprio(1);
#pragma unroll
    for (int n = 0; n < 4; ++n) {
      f32x4 a = {};
      int key = n * 16 + c_;
#pragma unroll
      for (int kc = 0; kc < 2; ++kc) {
        int slot = (kc * 4 + g_) ^ (key & 7);
        bf16x8 kf = *(const bf16x8*)(Kc + key * 64 + slot * 8);
        a = __builtin_amdgcn_mfma_f32_16x16x32_bf16(kf, qf[kc], a, 0, 0, 0);
      }
      s[n] = a;
    }
    __builtin_amdgcn_s_setprio(0);

    // ---- mask select (regs, no LDS) ----
#pragma unroll
    for (int n = 0; n < 4; ++n) {
      s[n][0] = mcur[n].x ? s[n][0] : -1e30f;
      s[n][1] = mcur[n].y ? s[n][1] : -1e30f;
      s[n][2] = mcur[n].z ? s[n][2] : -1e30f;
      s[n][3] = mcur[n].w ? s[n][3] : -1e30f;
    }

    // ---- shuffle-free online softmax fast path ----
    // per-lane max over this lane's 16 scores (no cross-lane traffic)
    float pmax = fmaxf(fmaxf(s[0][0], s[0][1]), fmaxf(s[0][2], s[0][3]));
#pragma unroll
    for (int n = 1; n < 4; ++n)
      pmax = fmaxf(pmax, fmaxf(fmaxf(s[n][0], s[n][1]), fmaxf(s[n][2], s[n][3])));

    if (!__all(pmax - mrun <= 8.f)) {
      // slow path (rare): true cross-lane row max, rescale state
      float pm = fmaxf(pmax, __shfl_xor(pmax, 16));
      pm = fmaxf(pm, __shfl_xor(pm, 32));      // common per q-row
      float mn = fmaxf(mrun, pm);
      float sc = __builtin_amdgcn_exp2f(mrun - mn);
      mrun = mn;                               // stays common per q-row
      lrun *= sc;
      float scB[4];
#pragma unroll
      for (int i = 0; i < 4; ++i) scB[i] = __shfl(sc, g_ * 4 + i);
#pragma unroll
      for (int n = 0; n < 4; ++n)
#pragma unroll
        for (int i = 0; i < 4; ++i) o[n][i] *= scB[i];
    }

    // p = exp2(s - mrun) (bounded by 2^8 on fast path), per-lane partial sum
    float lsum = 0.f;
#pragma unroll
    for (int n = 0; n < 4; ++n) {
      float p0 = __builtin_amdgcn_exp2f(s[n][0] - mrun);
      float p1 = __builtin_amdgcn_exp2f(s[n][1] - mrun);
      float p2 = __builtin_amdgcn_exp2f(s[n][2] - mrun);
      float p3 = __builtin_amdgcn_exp2f(s[n][3] - mrun);
      lsum += (p0 + p1) + (p2 + p3);
      uint2 pk;
      pk.x = cvt_pk_bf16(p0, p1);
      pk.y = cvt_pk_bf16(p2, p3);
      *(uint2*)(PwB + ((c_ * 128) | ((n * 32 + g_ * 8) ^ swz))) = pk;
    }
    lrun += lsum;

    // ---- O += P V ----
    __builtin_amdgcn_s_setprio(1);
#pragma unroll
    for (int ks = 0; ks < 2; ++ks) {
      bf16x8 pf = *(const bf16x8*)(PwB + ((c_ * 128) | ((ks * 64 + g_ * 16) ^ swz)));
#pragma unroll
      for (int n = 0; n < 4; ++n) {
        int d = n * 16 + c_;
        int slot = (ks * 4 + g_) ^ (d & 7);
        bf16x8 vf = *(const bf16x8*)(Vc + d * 64 + slot * 8);
        o[n] = __builtin_amdgcn_mfma_f32_16x16x32_bf16(pf, vf, o[n], 0, 0, 0);
      }
    }
    __builtin_amdgcn_s_setprio(0);

    __syncthreads();   // drains prefetch vmcnt + P lgkm, flips buffers
    cur ^= 1;
  }

  // ---- epilogue: reduce lrun partials once, then out = o / l ----
  lrun += __shfl_xor(lrun, 16);
  lrun += __shfl_xor(lrun, 32);     // now common per q-row (total over 2048 keys)
  float lB[4];
#pragma unroll
  for (int i = 0; i < 4; ++i) lB[i] = __shfl(lrun, g_ * 4 + i);
#pragma unroll
  for (int n = 0; n < 4; ++n) {
#pragma unroll
    for (int i = 0; i < 4; ++i) {
      int srow = qt * 64 + w * 16 + g_ * 4 + i;
      int d = n * 16 + c_;
      out[((size_t)b * SQn + srow) * DMn + h * 64 + d] = f2bf(o[n][i] / lB[i]);
    }
  }
#undef STAGE
}

// ---------------- launch ----------------
extern "C" void kernel_launch(void* const* d_in, const int* in_sizes, int n_in,
                              void* d_out, int out_size, void* d_ws, size_t ws_size,
                              hipStream_t stream) {
  const float* Q  = (const float*)d_in[0];
  const float* K  = (const float*)d_in[1];
  const float* V  = (const float*)d_in[2];
  const int* mask = (const int*)d_in[3];
  const float* Wq = (const float*)d_in[4];
  const float* bq = (const float*)d_in[5];
  const float* Wk = (const float*)d_in[6];
  const float* bk = (const float*)d_in[7];
  const float* Wv = (const float*)d_in[8];
  const float* bv = (const float*)d_in[9];
  const float* Wo = (const float*)d_in[10];
  const float* bo = (const float*)d_in[11];

  char* ws = (char*)d_ws;
  const size_t MB = 1024 * 1024;
  short* Qb  = (short*)(ws + 0 * MB);    // 3 x 8MB contiguous (fused cast out)
  short* Wqt = (short*)(ws + 24 * MB);   // 4 x 2MB contiguous (fused transpose out)
  short* Wkt = (short*)(ws + 26 * MB);
  short* Wvt = (short*)(ws + 28 * MB);
  short* Wot = (short*)(ws + 30 * MB);
  short* qp  = (short*)(ws + 32 * MB);   // [B][H][S][64], pre-scaled
  short* kp  = (short*)(ws + 40 * MB);   // [B][H][S][64]
  short* vpt = (short*)(ws + 48 * MB);   // [B][H][64][S]  (V^T)
  short* Kb  = Qb + 4 * MB;              // element offsets into fused cast region
  short* Vb  = Qb + 8 * MB;
  short* ao  = Qb;                       // alias: Qb dead after projection GEMM

  const int n4 = (2 * 2048 * 1024) / 4;  // per-tensor float4 count
  cast3_f32_bf16<<<3 * n4 / 256, 256, 0, stream>>>(Q, K, V, Qb, n4);

  transpose_cast4<<<dim3(32, 32, 4), dim3(32, 8), 0, stream>>>(Wq, Wk, Wv, Wo, Wqt);

  // fused 3-way projection GEMM (q scaled, V transposed in epilogue)
  gemm_bt3<<<dim3(32, 8, 3), 256, 0, stream>>>(Qb, Kb, Vb, Wqt, Wkt, Wvt,
                                               bq, bk, bv, qp, kp, vpt);

  attn<<<1024, 256, 0, stream>>>(qp, kp, vpt, mask, ao);

  // final projection -> f32 output, 128x64 tile = 512 blocks (2/CU)
  gemm_n64<<<dim3(32, 16), 256, 0, stream>>>(ao, Wot, bo, (float*)d_out);
}

// Round 10
// 148.737 us; speedup vs baseline: 1.0082x; 1.0082x over previous
//
#include <hip/hip_runtime.h>
#include <hip/hip_bf16.h>

// Problem constants
#define SQn 2048
#define SKn 2048
#define DMn 1024
#define NHn 16
#define DHn 64

typedef __attribute__((ext_vector_type(8))) short bf16x8;
typedef __attribute__((ext_vector_type(4))) float f32x4;

#define QSCALE 0.1803368801f  /* (1/sqrt(64)) / ln2 : folds softmax scale + exp->exp2 */

__device__ __forceinline__ short f2bf(float f) {
  union { float f; unsigned u; } a; a.f = f;
  return (short)((a.u + 0x7FFFu + ((a.u >> 16) & 1u)) >> 16);  // RNE
}

__device__ __forceinline__ unsigned cvt_pk_bf16(float lo, float hi) {
  unsigned r;
  asm("v_cvt_pk_bf16_f32 %0, %1, %2" : "=v"(r) : "v"(lo), "v"(hi));
  return r;
}

__device__ __forceinline__ void gload16(const void* g, void* l) {
  __builtin_amdgcn_global_load_lds(
      (__attribute__((address_space(1))) void*)g,
      (__attribute__((address_space(3))) void*)l, 16, 0, 0);
}

// ---------------- fused f32 -> bf16 cast for Q,K,V (one launch) ----------------
__global__ __launch_bounds__(256) void cast3_f32_bf16(const float* __restrict__ A,
                                                      const float* __restrict__ B,
                                                      const float* __restrict__ C,
                                                      short* __restrict__ out, int n4each) {
  int i = blockIdx.x * 256 + threadIdx.x;
  const float* src;
  int j = i;
  if (i < n4each) src = A;
  else if (i < 2 * n4each) { src = B; j = i - n4each; }
  else { src = C; j = i - 2 * n4each; }
  float4 f = ((const float4*)src)[j];
  short4 o;
  o.x = f2bf(f.x); o.y = f2bf(f.y); o.z = f2bf(f.z); o.w = f2bf(f.w);
  ((short4*)out)[i] = o;
}

// ---------------- W [K][N] f32 -> Wt [N][K] bf16, 4 weights in one launch --------
__global__ __launch_bounds__(256) void transpose_cast4(
    const float* __restrict__ W0, const float* __restrict__ W1,
    const float* __restrict__ W2, const float* __restrict__ W3,
    short* __restrict__ WtBase) {
  const int z = blockIdx.z;
  const float* W = (z == 0) ? W0 : (z == 1) ? W1 : (z == 2) ? W2 : W3;
  short* Wt = WtBase + (size_t)z * DMn * DMn;
  __shared__ float t[32][33];
  int bx = blockIdx.x * 32;  // N range
  int by = blockIdx.y * 32;  // K range
  int tx = threadIdx.x, ty = threadIdx.y;  // 32 x 8
#pragma unroll
  for (int j = 0; j < 4; ++j)
    t[ty + j * 8][tx] = W[(size_t)(by + ty + j * 8) * DMn + bx + tx];
  __syncthreads();
#pragma unroll
  for (int j = 0; j < 4; ++j)
    Wt[(size_t)(bx + ty + j * 8) * DMn + by + tx] = f2bf(t[tx][ty + j * 8]);
}

// ---------------- bf16 GEMM, single-buffer m97 structure, BK=64, T2-swizzled ----
// Projections: z=0 -> q scaled by QSCALE, [b][h][s][64]; z=1 -> k same layout;
//              z=2 -> V^T layout [b][h][d][s].
// LDS tiles [128][64] with 16B-chunk XOR swizzle: slot = chunk ^ (row&7),
// realized via pre-swizzled global SOURCE + swizzled ds_read (rule #21).
__global__ __launch_bounds__(256) void gemm_bt3(
    const short* __restrict__ A0, const short* __restrict__ A1, const short* __restrict__ A2,
    const short* __restrict__ B0, const short* __restrict__ B1, const short* __restrict__ B2,
    const float* __restrict__ c0, const float* __restrict__ c1, const float* __restrict__ c2,
    short* __restrict__ O0, short* __restrict__ O1, short* __restrict__ O2) {
  constexpr int K = 1024;
  const int z = blockIdx.z;
  const short* A  = (z == 0) ? A0 : (z == 1) ? A1 : A2;
  const short* Bt = (z == 0) ? B0 : (z == 1) ? B1 : B2;
  const float* bias = (z == 0) ? c0 : (z == 1) ? c1 : c2;
  short* Cout = (z == 0) ? O0 : (z == 1) ? O1 : O2;

  __shared__ short As[128 * 64];
  __shared__ short Bs[128 * 64];
  const int tid = threadIdx.x;
  const int lane = tid & 63;
  const int wid = tid >> 6;
  const int wr = wid >> 1, wc = wid & 1;
  const int bm = blockIdx.x * 128, bn = blockIdx.y * 128;

  f32x4 acc[4][4] = {};

  // staging: 1024 chunks (16B) per tile, 4 per thread.
  // Global offset for chunk c: row (c>>3) has GLOBAL stride K; swizzled
  // 16B-chunk index = (c&7) ^ (row&7).   (r9 bug: used LDS stride 64 here)
  size_t soff[4];
#pragma unroll
  for (int j = 0; j < 4; ++j) {
    int c = j * 256 + tid;
    int r = c >> 3;
    soff[j] = (size_t)r * K + (((c & 7) ^ (r & 7)) << 3);
  }
  const short* Ag = A + (size_t)bm * K;
  const short* Bg = Bt + (size_t)bn * K;

  const int rowA = wr * 64 + (lane & 15);
  const int rowB = wc * 64 + (lane & 15);
  const int l7 = lane & 7, g8 = lane >> 4;

  for (int k0 = 0; k0 < K; k0 += 64) {
    __syncthreads();
#pragma unroll
    for (int j = 0; j < 4; ++j) {
      gload16(Ag + soff[j] + k0, As + (j * 256 + wid * 64) * 8 + lane * 8);
      gload16(Bg + soff[j] + k0, Bs + (j * 256 + wid * 64) * 8 + lane * 8);
    }
    __syncthreads();

#pragma unroll
    for (int kc = 0; kc < 2; ++kc) {
      bf16x8 a[4], b[4];
      int ch = kc * 4 + g8;
#pragma unroll
      for (int m = 0; m < 4; ++m)
        a[m] = *(const bf16x8*)(As + (rowA + m * 16) * 64 + ((ch ^ l7) << 3));
#pragma unroll
      for (int n = 0; n < 4; ++n)
        b[n] = *(const bf16x8*)(Bs + (rowB + n * 16) * 64 + ((ch ^ l7) << 3));
#pragma unroll
      for (int m = 0; m < 4; ++m)
#pragma unroll
        for (int n = 0; n < 4; ++n)
          acc[m][n] = __builtin_amdgcn_mfma_f32_16x16x32_bf16(a[m], b[n], acc[m][n], 0, 0, 0);
    }
  }

  // epilogue: C/D layout col=lane&15, row=(lane>>4)*4+i
  const int crow0 = bm + wr * 64 + ((lane >> 4) * 4);
  const int ccol0 = bn + wc * 64 + (lane & 15);
#pragma unroll
  for (int m = 0; m < 4; ++m)
#pragma unroll
    for (int n = 0; n < 4; ++n) {
      int col = ccol0 + n * 16;
      float bv = bias[col];
#pragma unroll
      for (int i = 0; i < 4; ++i) {
        int row = crow0 + m * 16 + i;
        float val = acc[m][n][i] + bv;
        int bb = row >> 11, s = row & 2047;   // SQ=2048
        int hh = col >> 6, d = col & 63;      // DH=64
        if (z == 2) {  // V^T: [b][h][d][s]
          Cout[((((size_t)bb * NHn + hh) * DHn + d) << 11) + s] = f2bf(val);
        } else {
          if (z == 0) val *= QSCALE;          // fold softmax scale into q
          Cout[((((size_t)bb * NHn + hh) * SQn + s) << 6) + d] = f2bf(val);
        }
      }
    }
}

// ---------------- final GEMM, 128x64 tile, BK=64, single-buffer, swizzled -------
__global__ __launch_bounds__(256) void gemm_n64(const short* __restrict__ A,
                                                const short* __restrict__ Bt,
                                                const float* __restrict__ bias,
                                                float* __restrict__ C) {
  constexpr int K = 1024, N = 1024;
  __shared__ short As[128 * 64];
  __shared__ short Bs[64 * 64];
  const int tid = threadIdx.x;
  const int lane = tid & 63;
  const int wid = tid >> 6;
  const int wr = wid >> 1, wc = wid & 1;   // waves 2x2, wave tile 64x32
  const int bm = blockIdx.x * 128, bn = blockIdx.y * 64;

  f32x4 acc[4][2] = {};

  size_t soff[4];
#pragma unroll
  for (int j = 0; j < 4; ++j) {
    int c = j * 256 + tid;
    int r = c >> 3;
    soff[j] = (size_t)r * K + (((c & 7) ^ (r & 7)) << 3);
  }
  const short* Ag = A + (size_t)bm * K;
  const short* Bg = Bt + (size_t)bn * K;

  const int rowA = wr * 64 + (lane & 15);
  const int rowB = wc * 32 + (lane & 15);
  const int l7 = lane & 7, g8 = lane >> 4;

  for (int k0 = 0; k0 < K; k0 += 64) {
    __syncthreads();
#pragma unroll
    for (int j = 0; j < 4; ++j)
      gload16(Ag + soff[j] + k0, As + (j * 256 + wid * 64) * 8 + lane * 8);
#pragma unroll
    for (int j = 0; j < 2; ++j)
      gload16(Bg + soff[j] + k0, Bs + (j * 256 + wid * 64) * 8 + lane * 8);
    __syncthreads();

#pragma unroll
    for (int kc = 0; kc < 2; ++kc) {
      bf16x8 a[4], b[2];
      int ch = kc * 4 + g8;
#pragma unroll
      for (int m = 0; m < 4; ++m)
        a[m] = *(const bf16x8*)(As + (rowA + m * 16) * 64 + ((ch ^ l7) << 3));
#pragma unroll
      for (int n = 0; n < 2; ++n)
        b[n] = *(const bf16x8*)(Bs + (rowB + n * 16) * 64 + ((ch ^ l7) << 3));
#pragma unroll
      for (int m = 0; m < 4; ++m)
#pragma unroll
        for (int n = 0; n < 2; ++n)
          acc[m][n] = __builtin_amdgcn_mfma_f32_16x16x32_bf16(a[m], b[n], acc[m][n], 0, 0, 0);
    }
  }

  const int crow0 = bm + wr * 64 + ((lane >> 4) * 4);
  const int ccol0 = bn + wc * 32 + (lane & 15);
#pragma unroll
  for (int m = 0; m < 4; ++m)
#pragma unroll
    for (int n = 0; n < 2; ++n) {
      int col = ccol0 + n * 16;
      float bv = bias[col];
#pragma unroll
      for (int i = 0; i < 4; ++i) {
        int row = crow0 + m * 16 + i;
        C[(size_t)row * N + col] = acc[m][n][i] + bv;
      }
    }
}

// ---------------- fused masked flash attention, QBLK=128, 8 waves ----------------
// Swapped QK^T (lane owns one q row), double-buffered K/V, cvt_pk P-pack,
// shuffle-free fast path, per-lane lrun partials. Each 64-key tile serves 128 q
// rows -> K/V traffic and staging per q halved vs QBLK=64.
// LDS = 2*8K (K) + 2*8K (V) + 16K (P) = 49152.
__global__ __launch_bounds__(512) void attn(const short* __restrict__ q,
                                            const short* __restrict__ k,
                                            const short* __restrict__ vt,
                                            const int* __restrict__ mask,
                                            short* __restrict__ out) {
  __shared__ short Ks[2][64 * 64];   // [key][d], chunk-swizzled ^(key&7)
  __shared__ short Vs[2][64 * 64];   // [d][key], chunk-swizzled ^(d&7)
  __shared__ short Ps[8][16 * 64];   // per-wave P [16 q][64 key], 8B-slot XOR swizzle

  const int tid = threadIdx.x;
  const int lane = tid & 63;
  const int w = tid >> 6;            // 0..7
  // bijective XCD chunk remap: 512 blocks = 8 XCDs x 64; 4 heads per XCD
  // (K/V working set 4 x 512KB = 2MB fits one XCD's 4MB L2).
  const int l = (blockIdx.x & 7) * 64 + (blockIdx.x >> 3);
  const int bh = l >> 4;             // 0..31 = b*16+h
  const int qt = l & 15;             // 0..15, 128-row q tiles
  const int h = bh & 15;
  const int b = bh >> 4;
  const size_t hoff = (size_t)bh * (SQn * DHn);

  const int c_ = lane & 15, g_ = lane >> 4;
  const int swz = (c_ & 7) << 4;     // P-buffer byte swizzle (bits 4-6)

  // Q hoist (B-operand of swapped QK^T): wave's 16 q rows
  bf16x8 qf[2];
  {
    const short* qp = q + hoff + (size_t)(qt * 128 + w * 16 + c_) * DHn + g_ * 8;
    qf[0] = *(const bf16x8*)qp;
    qf[1] = *(const bf16x8*)(qp + 32);
  }

  // staging: 512 chunks per 64x64 tile, 1 per thread for each of K and V
  const int r0 = tid >> 3;
  const int gch = (tid & 7) ^ (r0 & 7);
  const size_t kO = (size_t)r0 * DHn + gch * 8;
  const size_t vO = (size_t)r0 * SKn + gch * 8;
  const int ldsO = tid * 8;

  const int* mrow = mask + (size_t)b * SKn;

  float mrun = -1e30f;   // running max, common across the 4 lanes of a q-row
  float lrun = 0.f;      // per-lane partial sum
  f32x4 o[4] = {};
  char* PwB = (char*)Ps[w];

#define STAGE(buf, kbase, vbase)            \
  gload16((kbase) + kO, &Ks[buf][ldsO]);    \
  gload16((vbase) + vO, &Vs[buf][ldsO]);

  // ---- prologue: stage tile 0 into buf 0, mask tile 0 into regs ----
  const short* kpre = k + hoff;
  const short* vpre = vt + hoff;
  int4 mnext[4];
  STAGE(0, kpre, vpre);
#pragma unroll
  for (int n = 0; n < 4; ++n) mnext[n] = *(const int4*)(mrow + n * 16 + g_ * 4);
  kpre += 64 * DHn;
  vpre += 64;
  const int* mpre = mrow + 64;
  __syncthreads();

  int cur = 0;
  for (int kt = 0; kt < SKn / 64; ++kt) {
    int4 mcur[4];
#pragma unroll
    for (int n = 0; n < 4; ++n) mcur[n] = mnext[n];

    // ---- prefetch tile kt+1 into buf^1 (flies under this tile's compute) ----
    if (kt + 1 < SKn / 64) {
      STAGE(cur ^ 1, kpre, vpre);
#pragma unroll
      for (int n = 0; n < 4; ++n) mnext[n] = *(const int4*)(mpre + n * 16 + g_ * 4);
      kpre += 64 * DHn;
      vpre += 64;
      mpre += 64;
    }

    const short* Kc = Ks[cur];
    const short* Vc = Vs[cur];

    // ---- S^T = K Q^T : lane holds S[q=c_][key = 16n + 4g_ + i] ----
    f32x4 s[4];
    __builtin_amdgcn_s_setprio(1);
#pragma unroll
    for (int n = 0; n < 4; ++n) {
      f32x4 a = {};
      int key = n * 16 + c_;
#pragma unroll
      for (int kc = 0; kc < 2; ++kc) {
        int slot = (kc * 4 + g_) ^ (key & 7);
        bf16x8 kf = *(const bf16x8*)(Kc + key * 64 + slot * 8);
        a = __builtin_amdgcn_mfma_f32_16x16x32_bf16(kf, qf[kc], a, 0, 0, 0);
      }
      s[n] = a;
    }
    __builtin_amdgcn_s_setprio(0);

    // ---- mask select (regs, no LDS) ----
#pragma unroll
    for (int n = 0; n < 4; ++n) {
      s[n][0] = mcur[n].x ? s[n][0] : -1e30f;
      s[n][1] = mcur[n].y ? s[n][1] : -1e30f;
      s[n][2] = mcur[n].z ? s[n][2] : -1e30f;
      s[n][3] = mcur[n].w ? s[n][3] : -1e30f;
    }

    // ---- shuffle-free online softmax fast path ----
    float pmax = fmaxf(fmaxf(s[0][0], s[0][1]), fmaxf(s[0][2], s[0][3]));
#pragma unroll
    for (int n = 1; n < 4; ++n)
      pmax = fmaxf(pmax, fmaxf(fmaxf(s[n][0], s[n][1]), fmaxf(s[n][2], s[n][3])));

    if (!__all(pmax - mrun <= 8.f)) {
      // slow path (rare): true cross-lane row max, rescale state
      float pm = fmaxf(pmax, __shfl_xor(pmax, 16));
      pm = fmaxf(pm, __shfl_xor(pm, 32));      // common per q-row
      float mn = fmaxf(mrun, pm);
      float sc = __builtin_amdgcn_exp2f(mrun - mn);
      mrun = mn;
      lrun *= sc;
      float scB[4];
#pragma unroll
      for (int i = 0; i < 4; ++i) scB[i] = __shfl(sc, g_ * 4 + i);
#pragma unroll
      for (int n = 0; n < 4; ++n)
#pragma unroll
        for (int i = 0; i < 4; ++i) o[n][i] *= scB[i];
    }

    // p = exp2(s - mrun), per-lane partial sum; pack via v_cvt_pk_bf16_f32
    float lsum = 0.f;
#pragma unroll
    for (int n = 0; n < 4; ++n) {
      float p0 = __builtin_amdgcn_exp2f(s[n][0] - mrun);
      float p1 = __builtin_amdgcn_exp2f(s[n][1] - mrun);
      float p2 = __builtin_amdgcn_exp2f(s[n][2] - mrun);
      float p3 = __builtin_amdgcn_exp2f(s[n][3] - mrun);
      lsum += (p0 + p1) + (p2 + p3);
      uint2 pk;
      pk.x = cvt_pk_bf16(p0, p1);
      pk.y = cvt_pk_bf16(p2, p3);
      *(uint2*)(PwB + ((c_ * 128) | ((n * 32 + g_ * 8) ^ swz))) = pk;
    }
    lrun += lsum;

    // ---- O += P V ----
    __builtin_amdgcn_s_setprio(1);
#pragma unroll
    for (int ks = 0; ks < 2; ++ks) {
      bf16x8 pf = *(const bf16x8*)(PwB + ((c_ * 128) | ((ks * 64 + g_ * 16) ^ swz)));
#pragma unroll
      for (int n = 0; n < 4; ++n) {
        int d = n * 16 + c_;
        int slot = (ks * 4 + g_) ^ (d & 7);
        bf16x8 vf = *(const bf16x8*)(Vc + d * 64 + slot * 8);
        o[n] = __builtin_amdgcn_mfma_f32_16x16x32_bf16(pf, vf, o[n], 0, 0, 0);
      }
    }
    __builtin_amdgcn_s_setprio(0);

    __syncthreads();   // drains prefetch vmcnt + P lgkm, flips buffers
    cur ^= 1;
  }

  // ---- epilogue: reduce lrun partials once, then out = o / l ----
  lrun += __shfl_xor(lrun, 16);
  lrun += __shfl_xor(lrun, 32);     // now common per q-row
  float lB[4];
#pragma unroll
  for (int i = 0; i < 4; ++i) lB[i] = __shfl(lrun, g_ * 4 + i);
#pragma unroll
  for (int n = 0; n < 4; ++n) {
#pragma unroll
    for (int i = 0; i < 4; ++i) {
      int srow = qt * 128 + w * 16 + g_ * 4 + i;
      int d = n * 16 + c_;
      out[((size_t)b * SQn + srow) * DMn + h * 64 + d] = f2bf(o[n][i] / lB[i]);
    }
  }
#undef STAGE
}

// ---------------- launch ----------------
extern "C" void kernel_launch(void* const* d_in, const int* in_sizes, int n_in,
                              void* d_out, int out_size, void* d_ws, size_t ws_size,
                              hipStream_t stream) {
  const float* Q  = (const float*)d_in[0];
  const float* K  = (const float*)d_in[1];
  const float* V  = (const float*)d_in[2];
  const int* mask = (const int*)d_in[3];
  const float* Wq = (const float*)d_in[4];
  const float* bq = (const float*)d_in[5];
  const float* Wk = (const float*)d_in[6];
  const float* bk = (const float*)d_in[7];
  const float* Wv = (const float*)d_in[8];
  const float* bv = (const float*)d_in[9];
  const float* Wo = (const float*)d_in[10];
  const float* bo = (const float*)d_in[11];

  char* ws = (char*)d_ws;
  const size_t MB = 1024 * 1024;
  short* Qb  = (short*)(ws + 0 * MB);    // 3 x 8MB contiguous (fused cast out)
  short* Wqt = (short*)(ws + 24 * MB);   // 4 x 2MB contiguous (fused transpose out)
  short* Wkt = (short*)(ws + 26 * MB);
  short* Wvt = (short*)(ws + 28 * MB);
  short* Wot = (short*)(ws + 30 * MB);
  short* qp  = (short*)(ws + 32 * MB);   // [B][H][S][64], pre-scaled
  short* kp  = (short*)(ws + 40 * MB);   // [B][H][S][64]
  short* vpt = (short*)(ws + 48 * MB);   // [B][H][64][S]  (V^T)
  short* Kb  = Qb + 4 * MB;              // element offsets into fused cast region
  short* Vb  = Qb + 8 * MB;
  short* ao  = Qb;                       // alias: Qb dead after projection GEMM

  const int n4 = (2 * 2048 * 1024) / 4;  // per-tensor float4 count
  cast3_f32_bf16<<<3 * n4 / 256, 256, 0, stream>>>(Q, K, V, Qb, n4);

  transpose_cast4<<<dim3(32, 32, 4), dim3(32, 8), 0, stream>>>(Wq, Wk, Wv, Wo, Wqt);

  // fused 3-way projection GEMM (q scaled, V transposed in epilogue)
  gemm_bt3<<<dim3(32, 8, 3), 256, 0, stream>>>(Qb, Kb, Vb, Wqt, Wkt, Wvt,
                                               bq, bk, bv, qp, kp, vpt);

  attn<<<512, 512, 0, stream>>>(qp, kp, vpt, mask, ao);

  // final projection -> f32 output, 128x64 tile = 512 blocks (2/CU)
  gemm_n64<<<dim3(32, 16), 256, 0, stream>>>(ao, Wot, bo, (float*)d_out);
}

// Round 11
// 139.811 us; speedup vs baseline: 1.0726x; 1.0638x over previous
//
#include <hip/hip_runtime.h>
#include <hip/hip_bf16.h>

// Problem constants
#define SQn 2048
#define SKn 2048
#define DMn 1024
#define NHn 16
#define DHn 64

typedef __attribute__((ext_vector_type(8))) short bf16x8;
typedef __attribute__((ext_vector_type(4))) float f32x4;

#define QSCALE 0.1803368801f  /* (1/sqrt(64)) / ln2 : folds softmax scale + exp->exp2 */

__device__ __forceinline__ short f2bf(float f) {
  union { float f; unsigned u; } a; a.f = f;
  return (short)((a.u + 0x7FFFu + ((a.u >> 16) & 1u)) >> 16);  // RNE
}

__device__ __forceinline__ unsigned cvt_pk_bf16(float lo, float hi) {
  unsigned r;
  asm("v_cvt_pk_bf16_f32 %0, %1, %2" : "=v"(r) : "v"(lo), "v"(hi));
  return r;
}

__device__ __forceinline__ void gload16(const void* g, void* l) {
  __builtin_amdgcn_global_load_lds(
      (__attribute__((address_space(1))) void*)g,
      (__attribute__((address_space(3))) void*)l, 16, 0, 0);
}

// ---------------- fused f32 -> bf16 cast for Q,K,V (one launch) ----------------
__global__ __launch_bounds__(256) void cast3_f32_bf16(const float* __restrict__ A,
                                                      const float* __restrict__ B,
                                                      const float* __restrict__ C,
                                                      short* __restrict__ out, int n4each) {
  int i = blockIdx.x * 256 + threadIdx.x;
  const float* src;
  int j = i;
  if (i < n4each) src = A;
  else if (i < 2 * n4each) { src = B; j = i - n4each; }
  else { src = C; j = i - 2 * n4each; }
  float4 f = ((const float4*)src)[j];
  short4 o;
  o.x = f2bf(f.x); o.y = f2bf(f.y); o.z = f2bf(f.z); o.w = f2bf(f.w);
  ((short4*)out)[i] = o;
}

// ---------------- W [K][N] f32 -> Wt [N][K] bf16, 4 weights in one launch --------
__global__ __launch_bounds__(256) void transpose_cast4(
    const float* __restrict__ W0, const float* __restrict__ W1,
    const float* __restrict__ W2, const float* __restrict__ W3,
    short* __restrict__ WtBase) {
  const int z = blockIdx.z;
  const float* W = (z == 0) ? W0 : (z == 1) ? W1 : (z == 2) ? W2 : W3;
  short* Wt = WtBase + (size_t)z * DMn * DMn;
  __shared__ float t[32][33];
  int bx = blockIdx.x * 32;  // N range
  int by = blockIdx.y * 32;  // K range
  int tx = threadIdx.x, ty = threadIdx.y;  // 32 x 8
#pragma unroll
  for (int j = 0; j < 4; ++j)
    t[ty + j * 8][tx] = W[(size_t)(by + ty + j * 8) * DMn + bx + tx];
  __syncthreads();
#pragma unroll
  for (int j = 0; j < 4; ++j)
    Wt[(size_t)(bx + ty + j * 8) * DMn + by + tx] = f2bf(t[tx][ty + j * 8]);
}

// ---------------- bf16 GEMM (m97 structure, BK=32, single-buffer) ---------------
// (r8's 2-phase dbuf: non-attn 69.4->77.2; r10's BK=64+swizzle: ->80. Reverted
//  to the r6-measured best. The [128][32] layout is conflict-free as-is.)
// Projections: z=0 -> q scaled by QSCALE, [b][h][s][64]; z=1 -> k same layout;
//              z=2 -> V^T layout [b][h][d][s].
__global__ __launch_bounds__(256) void gemm_bt3(
    const short* __restrict__ A0, const short* __restrict__ A1, const short* __restrict__ A2,
    const short* __restrict__ B0, const short* __restrict__ B1, const short* __restrict__ B2,
    const float* __restrict__ c0, const float* __restrict__ c1, const float* __restrict__ c2,
    short* __restrict__ O0, short* __restrict__ O1, short* __restrict__ O2) {
  constexpr int K = 1024;
  const int z = blockIdx.z;
  const short* A  = (z == 0) ? A0 : (z == 1) ? A1 : A2;
  const short* Bt = (z == 0) ? B0 : (z == 1) ? B1 : B2;
  const float* bias = (z == 0) ? c0 : (z == 1) ? c1 : c2;
  short* Cout = (z == 0) ? O0 : (z == 1) ? O1 : O2;

  __shared__ short As[128 * 32];
  __shared__ short Bs[128 * 32];
  const int tid = threadIdx.x;
  const int lane = tid & 63;
  const int wid = tid >> 6;
  const int wr = wid >> 1, wc = wid & 1;
  const int bm = blockIdx.x * 128, bn = blockIdx.y * 128;

  f32x4 acc[4][4] = {};

  const int srow = tid >> 2;
  const int scol = (tid & 3) * 8;
  const short* Ag = A + (size_t)bm * K;
  const short* Bg = Bt + (size_t)bn * K;

  for (int k0 = 0; k0 < K; k0 += 32) {
    __syncthreads();
    gload16(Ag + (size_t)srow * K + k0 + scol,        As + wid * 512);
    gload16(Ag + (size_t)(srow + 64) * K + k0 + scol, As + 2048 + wid * 512);
    gload16(Bg + (size_t)srow * K + k0 + scol,        Bs + wid * 512);
    gload16(Bg + (size_t)(srow + 64) * K + k0 + scol, Bs + 2048 + wid * 512);
    __syncthreads();

    bf16x8 a[4], b[4];
    const int rowA = wr * 64 + (lane & 15);
    const int rowB = wc * 64 + (lane & 15);
    const int ko = (lane >> 4) * 8;
#pragma unroll
    for (int m = 0; m < 4; ++m) a[m] = *(const bf16x8*)(As + (rowA + m * 16) * 32 + ko);
#pragma unroll
    for (int n = 0; n < 4; ++n) b[n] = *(const bf16x8*)(Bs + (rowB + n * 16) * 32 + ko);
#pragma unroll
    for (int m = 0; m < 4; ++m)
#pragma unroll
      for (int n = 0; n < 4; ++n)
        acc[m][n] = __builtin_amdgcn_mfma_f32_16x16x32_bf16(a[m], b[n], acc[m][n], 0, 0, 0);
  }

  // epilogue: C/D layout col=lane&15, row=(lane>>4)*4+i
  const int crow0 = bm + wr * 64 + ((lane >> 4) * 4);
  const int ccol0 = bn + wc * 64 + (lane & 15);
#pragma unroll
  for (int m = 0; m < 4; ++m)
#pragma unroll
    for (int n = 0; n < 4; ++n) {
      int col = ccol0 + n * 16;
      float bv = bias[col];
#pragma unroll
      for (int i = 0; i < 4; ++i) {
        int row = crow0 + m * 16 + i;
        float val = acc[m][n][i] + bv;
        int bb = row >> 11, s = row & 2047;   // SQ=2048
        int hh = col >> 6, d = col & 63;      // DH=64
        if (z == 2) {  // V^T: [b][h][d][s]
          Cout[((((size_t)bb * NHn + hh) * DHn + d) << 11) + s] = f2bf(val);
        } else {
          if (z == 0) val *= QSCALE;          // fold softmax scale into q
          Cout[((((size_t)bb * NHn + hh) * SQn + s) << 6) + d] = f2bf(val);
        }
      }
    }
}

// ---------------- final GEMM, 128x64 tile, BK=32, single-buffer -----------------
__global__ __launch_bounds__(256) void gemm_n64(const short* __restrict__ A,
                                                const short* __restrict__ Bt,
                                                const float* __restrict__ bias,
                                                float* __restrict__ C) {
  constexpr int K = 1024, N = 1024;
  __shared__ short As[128 * 32];
  __shared__ short Bs[64 * 32];
  const int tid = threadIdx.x;
  const int lane = tid & 63;
  const int wid = tid >> 6;
  const int wr = wid >> 1, wc = wid & 1;   // waves 2x2, wave tile 64x32
  const int bm = blockIdx.x * 128, bn = blockIdx.y * 64;

  f32x4 acc[4][2] = {};

  const int srow = tid >> 2;
  const int scol = (tid & 3) * 8;
  const short* Ag = A + (size_t)bm * K;
  const short* Bg = Bt + (size_t)bn * K;

  for (int k0 = 0; k0 < K; k0 += 32) {
    __syncthreads();
    gload16(Ag + (size_t)srow * K + k0 + scol,        As + wid * 512);
    gload16(Ag + (size_t)(srow + 64) * K + k0 + scol, As + 2048 + wid * 512);
    gload16(Bg + (size_t)srow * K + k0 + scol,        Bs + wid * 512);
    __syncthreads();

    bf16x8 a[4], b[2];
    const int rowA = wr * 64 + (lane & 15);
    const int rowB = wc * 32 + (lane & 15);
    const int ko = (lane >> 4) * 8;
#pragma unroll
    for (int m = 0; m < 4; ++m) a[m] = *(const bf16x8*)(As + (rowA + m * 16) * 32 + ko);
#pragma unroll
    for (int n = 0; n < 2; ++n) b[n] = *(const bf16x8*)(Bs + (rowB + n * 16) * 32 + ko);
#pragma unroll
    for (int m = 0; m < 4; ++m)
#pragma unroll
      for (int n = 0; n < 2; ++n)
        acc[m][n] = __builtin_amdgcn_mfma_f32_16x16x32_bf16(a[m], b[n], acc[m][n], 0, 0, 0);
  }

  const int crow0 = bm + wr * 64 + ((lane >> 4) * 4);
  const int ccol0 = bn + wc * 32 + (lane & 15);
#pragma unroll
  for (int m = 0; m < 4; ++m)
#pragma unroll
    for (int n = 0; n < 2; ++n) {
      int col = ccol0 + n * 16;
      float bv = bias[col];
#pragma unroll
      for (int i = 0; i < 4; ++i) {
        int row = crow0 + m * 16 + i;
        C[(size_t)row * N + col] = acc[m][n][i] + bv;
      }
    }
}

// ---------------- fused masked flash attention, QBLK=128, 8 waves ----------------
// (r10-verified: 68.7 us. Swapped QK^T, dbuf K/V, cvt_pk P-pack, shuffle-free
//  fast path, per-lane lrun partials, bijective XCD head placement.)
// LDS = 2*8K (K) + 2*8K (V) + 16K (P) = 49152.
__global__ __launch_bounds__(512) void attn(const short* __restrict__ q,
                                            const short* __restrict__ k,
                                            const short* __restrict__ vt,
                                            const int* __restrict__ mask,
                                            short* __restrict__ out) {
  __shared__ short Ks[2][64 * 64];   // [key][d], chunk-swizzled ^(key&7)
  __shared__ short Vs[2][64 * 64];   // [d][key], chunk-swizzled ^(d&7)
  __shared__ short Ps[8][16 * 64];   // per-wave P [16 q][64 key], 8B-slot XOR swizzle

  const int tid = threadIdx.x;
  const int lane = tid & 63;
  const int w = tid >> 6;            // 0..7
  const int l = (blockIdx.x & 7) * 64 + (blockIdx.x >> 3);
  const int bh = l >> 4;             // 0..31 = b*16+h
  const int qt = l & 15;             // 0..15, 128-row q tiles
  const int h = bh & 15;
  const int b = bh >> 4;
  const size_t hoff = (size_t)bh * (SQn * DHn);

  const int c_ = lane & 15, g_ = lane >> 4;
  const int swz = (c_ & 7) << 4;     // P-buffer byte swizzle (bits 4-6)

  // Q hoist (B-operand of swapped QK^T): wave's 16 q rows
  bf16x8 qf[2];
  {
    const short* qp = q + hoff + (size_t)(qt * 128 + w * 16 + c_) * DHn + g_ * 8;
    qf[0] = *(const bf16x8*)qp;
    qf[1] = *(const bf16x8*)(qp + 32);
  }

  // staging: 512 chunks per 64x64 tile, 1 per thread for each of K and V
  const int r0 = tid >> 3;
  const int gch = (tid & 7) ^ (r0 & 7);
  const size_t kO = (size_t)r0 * DHn + gch * 8;
  const size_t vO = (size_t)r0 * SKn + gch * 8;
  const int ldsO = tid * 8;

  const int* mrow = mask + (size_t)b * SKn;

  float mrun = -1e30f;   // running max, common across the 4 lanes of a q-row
  float lrun = 0.f;      // per-lane partial sum
  f32x4 o[4] = {};
  char* PwB = (char*)Ps[w];

#define STAGE(buf, kbase, vbase)            \
  gload16((kbase) + kO, &Ks[buf][ldsO]);    \
  gload16((vbase) + vO, &Vs[buf][ldsO]);

  // ---- prologue: stage tile 0 into buf 0, mask tile 0 into regs ----
  const short* kpre = k + hoff;
  const short* vpre = vt + hoff;
  int4 mnext[4];
  STAGE(0, kpre, vpre);
#pragma unroll
  for (int n = 0; n < 4; ++n) mnext[n] = *(const int4*)(mrow + n * 16 + g_ * 4);
  kpre += 64 * DHn;
  vpre += 64;
  const int* mpre = mrow + 64;
  __syncthreads();

  int cur = 0;
  for (int kt = 0; kt < SKn / 64; ++kt) {
    int4 mcur[4];
#pragma unroll
    for (int n = 0; n < 4; ++n) mcur[n] = mnext[n];

    // ---- prefetch tile kt+1 into buf^1 (flies under this tile's compute) ----
    if (kt + 1 < SKn / 64) {
      STAGE(cur ^ 1, kpre, vpre);
#pragma unroll
      for (int n = 0; n < 4; ++n) mnext[n] = *(const int4*)(mpre + n * 16 + g_ * 4);
      kpre += 64 * DHn;
      vpre += 64;
      mpre += 64;
    }

    const short* Kc = Ks[cur];
    const short* Vc = Vs[cur];

    // ---- S^T = K Q^T : lane holds S[q=c_][key = 16n + 4g_ + i] ----
    f32x4 s[4];
    __builtin_amdgcn_s_setprio(1);
#pragma unroll
    for (int n = 0; n < 4; ++n) {
      f32x4 a = {};
      int key = n * 16 + c_;
#pragma unroll
      for (int kc = 0; kc < 2; ++kc) {
        int slot = (kc * 4 + g_) ^ (key & 7);
        bf16x8 kf = *(const bf16x8*)(Kc + key * 64 + slot * 8);
        a = __builtin_amdgcn_mfma_f32_16x16x32_bf16(kf, qf[kc], a, 0, 0, 0);
      }
      s[n] = a;
    }
    __builtin_amdgcn_s_setprio(0);

    // ---- mask select (regs, no LDS) ----
#pragma unroll
    for (int n = 0; n < 4; ++n) {
      s[n][0] = mcur[n].x ? s[n][0] : -1e30f;
      s[n][1] = mcur[n].y ? s[n][1] : -1e30f;
      s[n][2] = mcur[n].z ? s[n][2] : -1e30f;
      s[n][3] = mcur[n].w ? s[n][3] : -1e30f;
    }

    // ---- shuffle-free online softmax fast path ----
    float pmax = fmaxf(fmaxf(s[0][0], s[0][1]), fmaxf(s[0][2], s[0][3]));
#pragma unroll
    for (int n = 1; n < 4; ++n)
      pmax = fmaxf(pmax, fmaxf(fmaxf(s[n][0], s[n][1]), fmaxf(s[n][2], s[n][3])));

    if (!__all(pmax - mrun <= 8.f)) {
      // slow path (rare): true cross-lane row max, rescale state
      float pm = fmaxf(pmax, __shfl_xor(pmax, 16));
      pm = fmaxf(pm, __shfl_xor(pm, 32));      // common per q-row
      float mn = fmaxf(mrun, pm);
      float sc = __builtin_amdgcn_exp2f(mrun - mn);
      mrun = mn;
      lrun *= sc;
      float scB[4];
#pragma unroll
      for (int i = 0; i < 4; ++i) scB[i] = __shfl(sc, g_ * 4 + i);
#pragma unroll
      for (int n = 0; n < 4; ++n)
#pragma unroll
        for (int i = 0; i < 4; ++i) o[n][i] *= scB[i];
    }

    // p = exp2(s - mrun), per-lane partial sum; pack via v_cvt_pk_bf16_f32
    float lsum = 0.f;
#pragma unroll
    for (int n = 0; n < 4; ++n) {
      float p0 = __builtin_amdgcn_exp2f(s[n][0] - mrun);
      float p1 = __builtin_amdgcn_exp2f(s[n][1] - mrun);
      float p2 = __builtin_amdgcn_exp2f(s[n][2] - mrun);
      float p3 = __builtin_amdgcn_exp2f(s[n][3] - mrun);
      lsum += (p0 + p1) + (p2 + p3);
      uint2 pk;
      pk.x = cvt_pk_bf16(p0, p1);
      pk.y = cvt_pk_bf16(p2, p3);
      *(uint2*)(PwB + ((c_ * 128) | ((n * 32 + g_ * 8) ^ swz))) = pk;
    }
    lrun += lsum;

    // ---- O += P V ----
    __builtin_amdgcn_s_setprio(1);
#pragma unroll
    for (int ks = 0; ks < 2; ++ks) {
      bf16x8 pf = *(const bf16x8*)(PwB + ((c_ * 128) | ((ks * 64 + g_ * 16) ^ swz)));
#pragma unroll
      for (int n = 0; n < 4; ++n) {
        int d = n * 16 + c_;
        int slot = (ks * 4 + g_) ^ (d & 7);
        bf16x8 vf = *(const bf16x8*)(Vc + d * 64 + slot * 8);
        o[n] = __builtin_amdgcn_mfma_f32_16x16x32_bf16(pf, vf, o[n], 0, 0, 0);
      }
    }
    __builtin_amdgcn_s_setprio(0);

    __syncthreads();   // drains prefetch vmcnt + P lgkm, flips buffers
    cur ^= 1;
  }

  // ---- epilogue: reduce lrun partials once, then out = o / l ----
  lrun += __shfl_xor(lrun, 16);
  lrun += __shfl_xor(lrun, 32);     // now common per q-row
  float lB[4];
#pragma unroll
  for (int i = 0; i < 4; ++i) lB[i] = __shfl(lrun, g_ * 4 + i);
#pragma unroll
  for (int n = 0; n < 4; ++n) {
#pragma unroll
    for (int i = 0; i < 4; ++i) {
      int srow = qt * 128 + w * 16 + g_ * 4 + i;
      int d = n * 16 + c_;
      out[((size_t)b * SQn + srow) * DMn + h * 64 + d] = f2bf(o[n][i] / lB[i]);
    }
  }
#undef STAGE
}

// ---------------- launch ----------------
extern "C" void kernel_launch(void* const* d_in, const int* in_sizes, int n_in,
                              void* d_out, int out_size, void* d_ws, size_t ws_size,
                              hipStream_t stream) {
  const float* Q  = (const float*)d_in[0];
  const float* K  = (const float*)d_in[1];
  const float* V  = (const float*)d_in[2];
  const int* mask = (const int*)d_in[3];
  const float* Wq = (const float*)d_in[4];
  const float* bq = (const float*)d_in[5];
  const float* Wk = (const float*)d_in[6];
  const float* bk = (const float*)d_in[7];
  const float* Wv = (const float*)d_in[8];
  const float* bv = (const float*)d_in[9];
  const float* Wo = (const float*)d_in[10];
  const float* bo = (const float*)d_in[11];

  char* ws = (char*)d_ws;
  const size_t MB = 1024 * 1024;
  short* Qb  = (short*)(ws + 0 * MB);    // 3 x 8MB contiguous (fused cast out)
  short* Wqt = (short*)(ws + 24 * MB);   // 4 x 2MB contiguous (fused transpose out)
  short* Wkt = (short*)(ws + 26 * MB);
  short* Wvt = (short*)(ws + 28 * MB);
  short* Wot = (short*)(ws + 30 * MB);
  short* qp  = (short*)(ws + 32 * MB);   // [B][H][S][64], pre-scaled
  short* kp  = (short*)(ws + 40 * MB);   // [B][H][S][64]
  short* vpt = (short*)(ws + 48 * MB);   // [B][H][64][S]  (V^T)
  short* Kb  = Qb + 4 * MB;              // element offsets into fused cast region
  short* Vb  = Qb + 8 * MB;
  short* ao  = Qb;                       // alias: Qb dead after projection GEMM

  const int n4 = (2 * 2048 * 1024) / 4;  // per-tensor float4 count
  cast3_f32_bf16<<<3 * n4 / 256, 256, 0, stream>>>(Q, K, V, Qb, n4);

  transpose_cast4<<<dim3(32, 32, 4), dim3(32, 8), 0, stream>>>(Wq, Wk, Wv, Wo, Wqt);

  // fused 3-way projection GEMM (q scaled, V transposed in epilogue)
  gemm_bt3<<<dim3(32, 8, 3), 256, 0, stream>>>(Qb, Kb, Vb, Wqt, Wkt, Wvt,
                                               bq, bk, bv, qp, kp, vpt);

  attn<<<512, 512, 0, stream>>>(qp, kp, vpt, mask, ao);

  // final projection -> f32 output, 128x64 tile = 512 blocks (2/CU)
  gemm_n64<<<dim3(32, 16), 256, 0, stream>>>(ao, Wot, bo, (float*)d_out);
}

// Round 12
// 121.599 us; speedup vs baseline: 1.2332x; 1.1498x over previous
//
#include <hip/hip_runtime.h>
#include <hip/hip_bf16.h>

// Problem constants
#define SQn 2048
#define SKn 2048
#define DMn 1024
#define NHn 16
#define DHn 64

typedef __attribute__((ext_vector_type(8))) short bf16x8;
typedef __attribute__((ext_vector_type(4))) float f32x4;

#define QSCALE 0.1803368801f  /* (1/sqrt(64)) / ln2 : folds softmax scale + exp->exp2 */

__device__ __forceinline__ short f2bf(float f) {
  union { float f; unsigned u; } a; a.f = f;
  return (short)((a.u + 0x7FFFu + ((a.u >> 16) & 1u)) >> 16);  // RNE
}

__device__ __forceinline__ unsigned cvt_pk_bf16(float lo, float hi) {
  unsigned r;
  asm("v_cvt_pk_bf16_f32 %0, %1, %2" : "=v"(r) : "v"(lo), "v"(hi));
  return r;
}

__device__ __forceinline__ void gload16(const void* g, void* l) {
  __builtin_amdgcn_global_load_lds(
      (__attribute__((address_space(1))) void*)g,
      (__attribute__((address_space(3))) void*)l, 16, 0, 0);
}

// ---------------- fused f32 -> bf16 cast for Q,K,V (one launch) ----------------
__global__ __launch_bounds__(256) void cast3_f32_bf16(const float* __restrict__ A,
                                                      const float* __restrict__ B,
                                                      const float* __restrict__ C,
                                                      short* __restrict__ out, int n4each) {
  int i = blockIdx.x * 256 + threadIdx.x;
  const float* src;
  int j = i;
  if (i < n4each) src = A;
  else if (i < 2 * n4each) { src = B; j = i - n4each; }
  else { src = C; j = i - 2 * n4each; }
  float4 f = ((const float4*)src)[j];
  short4 o;
  o.x = f2bf(f.x); o.y = f2bf(f.y); o.z = f2bf(f.z); o.w = f2bf(f.w);
  ((short4*)out)[i] = o;
}

// ---------------- W [K][N] f32 -> Wt [N][K] bf16, 4 weights in one launch --------
__global__ __launch_bounds__(256) void transpose_cast4(
    const float* __restrict__ W0, const float* __restrict__ W1,
    const float* __restrict__ W2, const float* __restrict__ W3,
    short* __restrict__ WtBase) {
  const int z = blockIdx.z;
  const float* W = (z == 0) ? W0 : (z == 1) ? W1 : (z == 2) ? W2 : W3;
  short* Wt = WtBase + (size_t)z * DMn * DMn;
  __shared__ float t[32][33];
  int bx = blockIdx.x * 32;  // N range
  int by = blockIdx.y * 32;  // K range
  int tx = threadIdx.x, ty = threadIdx.y;  // 32 x 8
#pragma unroll
  for (int j = 0; j < 4; ++j)
    t[ty + j * 8][tx] = W[(size_t)(by + ty + j * 8) * DMn + bx + tx];
  __syncthreads();
#pragma unroll
  for (int j = 0; j < 4; ++j)
    Wt[(size_t)(bx + ty + j * 8) * DMn + by + tx] = f2bf(t[tx][ty + j * 8]);
}

// ---------------- per-batch mask prefix scan -> pos[], L ----------------
// pos[b][s] = # valid keys before s; Lb[b] = total valid keys.
__global__ __launch_bounds__(256) void mask_scan(const int* __restrict__ mask,
                                                 int* __restrict__ pos,
                                                 int* __restrict__ Lb) {
  __shared__ int part[256];
  __shared__ int base[256];
  const int b = blockIdx.x;
  const int t = threadIdx.x;
  const int* m = mask + b * SKn;
  int v[8];
  int s0 = 0;
#pragma unroll
  for (int j = 0; j < 8; ++j) { v[j] = m[t * 8 + j] ? 1 : 0; s0 += v[j]; }
  part[t] = s0;
  __syncthreads();
  if (t == 0) {
    int acc = 0;
    for (int i = 0; i < 256; ++i) { base[i] = acc; acc += part[i]; }
    Lb[b] = acc;
  }
  __syncthreads();
  int acc = base[t];
  int* p = pos + b * SKn;
#pragma unroll
  for (int j = 0; j < 8; ++j) { p[t * 8 + j] = acc; acc += v[j]; }
}

// ---------------- bf16 GEMM (m97 structure, BK=32, single-buffer) ---------------
// Projections: z=0 -> q scaled by QSCALE, [b][h][s][64]; z=1 -> k, s remapped by
// stable partition (valid keys first); z=2 -> V^T layout [b][h][d][s_c], same remap.
__global__ __launch_bounds__(256) void gemm_bt3(
    const short* __restrict__ A0, const short* __restrict__ A1, const short* __restrict__ A2,
    const short* __restrict__ B0, const short* __restrict__ B1, const short* __restrict__ B2,
    const float* __restrict__ c0, const float* __restrict__ c1, const float* __restrict__ c2,
    short* __restrict__ O0, short* __restrict__ O1, short* __restrict__ O2,
    const int* __restrict__ maskp, const int* __restrict__ posp,
    const int* __restrict__ Lp) {
  constexpr int K = 1024;
  const int z = blockIdx.z;
  const short* A  = (z == 0) ? A0 : (z == 1) ? A1 : A2;
  const short* Bt = (z == 0) ? B0 : (z == 1) ? B1 : B2;
  const float* bias = (z == 0) ? c0 : (z == 1) ? c1 : c2;
  short* Cout = (z == 0) ? O0 : (z == 1) ? O1 : O2;

  __shared__ short As[128 * 32];
  __shared__ short Bs[128 * 32];
  const int tid = threadIdx.x;
  const int lane = tid & 63;
  const int wid = tid >> 6;
  const int wr = wid >> 1, wc = wid & 1;
  const int bm = blockIdx.x * 128, bn = blockIdx.y * 128;

  f32x4 acc[4][4] = {};

  const int srow = tid >> 2;
  const int scol = (tid & 3) * 8;
  const short* Ag = A + (size_t)bm * K;
  const short* Bg = Bt + (size_t)bn * K;

  for (int k0 = 0; k0 < K; k0 += 32) {
    __syncthreads();
    gload16(Ag + (size_t)srow * K + k0 + scol,        As + wid * 512);
    gload16(Ag + (size_t)(srow + 64) * K + k0 + scol, As + 2048 + wid * 512);
    gload16(Bg + (size_t)srow * K + k0 + scol,        Bs + wid * 512);
    gload16(Bg + (size_t)(srow + 64) * K + k0 + scol, Bs + 2048 + wid * 512);
    __syncthreads();

    bf16x8 a[4], b[4];
    const int rowA = wr * 64 + (lane & 15);
    const int rowB = wc * 64 + (lane & 15);
    const int ko = (lane >> 4) * 8;
#pragma unroll
    for (int m = 0; m < 4; ++m) a[m] = *(const bf16x8*)(As + (rowA + m * 16) * 32 + ko);
#pragma unroll
    for (int n = 0; n < 4; ++n) b[n] = *(const bf16x8*)(Bs + (rowB + n * 16) * 32 + ko);
#pragma unroll
    for (int m = 0; m < 4; ++m)
#pragma unroll
      for (int n = 0; n < 4; ++n)
        acc[m][n] = __builtin_amdgcn_mfma_f32_16x16x32_bf16(a[m], b[n], acc[m][n], 0, 0, 0);
  }

  // epilogue: C/D layout col=lane&15, row=(lane>>4)*4+i
  const int crow0 = bm + wr * 64 + ((lane >> 4) * 4);
  const int ccol0 = bn + wc * 64 + (lane & 15);
  float bv[4];
#pragma unroll
  for (int n = 0; n < 4; ++n) bv[n] = bias[ccol0 + n * 16];
#pragma unroll
  for (int m = 0; m < 4; ++m)
#pragma unroll
    for (int i = 0; i < 4; ++i) {
      int row = crow0 + m * 16 + i;
      int bb = row >> 11, s = row & 2047;   // SQ=2048
      if (z != 0) {  // stable-partition remap: valid keys -> [0,L), invalid -> [L,2048)
        int mm = maskp[(bb << 11) + s];
        int pp = posp[(bb << 11) + s];
        s = mm ? pp : (Lp[bb] + s - pp);
      }
#pragma unroll
      for (int n = 0; n < 4; ++n) {
        int col = ccol0 + n * 16;
        float val = acc[m][n][i] + bv[n];
        int hh = col >> 6, d = col & 63;    // DH=64
        if (z == 2) {  // V^T: [b][h][d][s_c]
          Cout[((((size_t)bb * NHn + hh) * DHn + d) << 11) + s] = f2bf(val);
        } else {
          if (z == 0) val *= QSCALE;        // fold softmax scale into q
          Cout[((((size_t)bb * NHn + hh) * SQn + s) << 6) + d] = f2bf(val);
        }
      }
    }
}

// ---------------- final GEMM, 128x64 tile, BK=32, single-buffer -----------------
__global__ __launch_bounds__(256) void gemm_n64(const short* __restrict__ A,
                                                const short* __restrict__ Bt,
                                                const float* __restrict__ bias,
                                                float* __restrict__ C) {
  constexpr int K = 1024, N = 1024;
  __shared__ short As[128 * 32];
  __shared__ short Bs[64 * 32];
  const int tid = threadIdx.x;
  const int lane = tid & 63;
  const int wid = tid >> 6;
  const int wr = wid >> 1, wc = wid & 1;   // waves 2x2, wave tile 64x32
  const int bm = blockIdx.x * 128, bn = blockIdx.y * 64;

  f32x4 acc[4][2] = {};

  const int srow = tid >> 2;
  const int scol = (tid & 3) * 8;
  const short* Ag = A + (size_t)bm * K;
  const short* Bg = Bt + (size_t)bn * K;

  for (int k0 = 0; k0 < K; k0 += 32) {
    __syncthreads();
    gload16(Ag + (size_t)srow * K + k0 + scol,        As + wid * 512);
    gload16(Ag + (size_t)(srow + 64) * K + k0 + scol, As + 2048 + wid * 512);
    gload16(Bg + (size_t)srow * K + k0 + scol,        Bs + wid * 512);
    __syncthreads();

    bf16x8 a[4], b[2];
    const int rowA = wr * 64 + (lane & 15);
    const int rowB = wc * 32 + (lane & 15);
    const int ko = (lane >> 4) * 8;
#pragma unroll
    for (int m = 0; m < 4; ++m) a[m] = *(const bf16x8*)(As + (rowA + m * 16) * 32 + ko);
#pragma unroll
    for (int n = 0; n < 2; ++n) b[n] = *(const bf16x8*)(Bs + (rowB + n * 16) * 32 + ko);
#pragma unroll
    for (int m = 0; m < 4; ++m)
#pragma unroll
      for (int n = 0; n < 2; ++n)
        acc[m][n] = __builtin_amdgcn_mfma_f32_16x16x32_bf16(a[m], b[n], acc[m][n], 0, 0, 0);
  }

  const int crow0 = bm + wr * 64 + ((lane >> 4) * 4);
  const int ccol0 = bn + wc * 32 + (lane & 15);
#pragma unroll
  for (int m = 0; m < 4; ++m)
#pragma unroll
    for (int n = 0; n < 2; ++n) {
      int col = ccol0 + n * 16;
      float bv = bias[col];
#pragma unroll
      for (int i = 0; i < 4; ++i) {
        int row = crow0 + m * 16 + i;
        C[(size_t)row * N + col] = acc[m][n][i] + bv;
      }
    }
}

// ---------------- fused flash attention over COMPACTED keys ----------------
// K/V pre-compacted (valid keys in [0,L)); no mask loads. Loop ceil(L/64) tiles;
// only the last tile needs an index guard. Otherwise identical to the r10-verified
// structure (swapped QK^T, dbuf K/V, cvt_pk P-pack, shuffle-free fast path).
// LDS = 2*8K (K) + 2*8K (V) + 16K (P) = 49152.
__global__ __launch_bounds__(512) void attn(const short* __restrict__ q,
                                            const short* __restrict__ k,
                                            const short* __restrict__ vt,
                                            const int* __restrict__ Lb,
                                            short* __restrict__ out) {
  __shared__ short Ks[2][64 * 64];   // [key][d], chunk-swizzled ^(key&7)
  __shared__ short Vs[2][64 * 64];   // [d][key], chunk-swizzled ^(d&7)
  __shared__ short Ps[8][16 * 64];   // per-wave P [16 q][64 key], 8B-slot XOR swizzle

  const int tid = threadIdx.x;
  const int lane = tid & 63;
  const int w = tid >> 6;            // 0..7
  const int l = (blockIdx.x & 7) * 64 + (blockIdx.x >> 3);  // bijective XCD remap
  const int bh = l >> 4;             // 0..31 = b*16+h
  const int qt = l & 15;             // 0..15, 128-row q tiles
  const int h = bh & 15;
  const int b = bh >> 4;
  const size_t hoff = (size_t)bh * (SQn * DHn);

  const int c_ = lane & 15, g_ = lane >> 4;
  const int swz = (c_ & 7) << 4;     // P-buffer byte swizzle (bits 4-6)

  const int L = Lb[b];
  const int nt = (L + 63) >> 6;
  const int lastt = nt - 1;

  // Q hoist (B-operand of swapped QK^T): wave's 16 q rows
  bf16x8 qf[2];
  {
    const short* qp = q + hoff + (size_t)(qt * 128 + w * 16 + c_) * DHn + g_ * 8;
    qf[0] = *(const bf16x8*)qp;
    qf[1] = *(const bf16x8*)(qp + 32);
  }

  // staging: 512 chunks per 64x64 tile, 1 per thread for each of K and V
  const int r0 = tid >> 3;
  const int gch = (tid & 7) ^ (r0 & 7);
  const size_t kO = (size_t)r0 * DHn + gch * 8;
  const size_t vO = (size_t)r0 * SKn + gch * 8;
  const int ldsO = tid * 8;

  float mrun = -1e30f;   // running max, common across the 4 lanes of a q-row
  float lrun = 0.f;      // per-lane partial sum
  f32x4 o[4] = {};
  char* PwB = (char*)Ps[w];

#define STAGE(buf, kbase, vbase)            \
  gload16((kbase) + kO, &Ks[buf][ldsO]);    \
  gload16((vbase) + vO, &Vs[buf][ldsO]);

  // ---- prologue: stage tile 0 into buf 0 ----
  const short* kpre = k + hoff;
  const short* vpre = vt + hoff;
  STAGE(0, kpre, vpre);
  kpre += 64 * DHn;
  vpre += 64;
  __syncthreads();

  int cur = 0;
  for (int kt = 0; kt < nt; ++kt) {
    // ---- prefetch tile kt+1 into buf^1 (flies under this tile's compute) ----
    if (kt + 1 < nt) {
      STAGE(cur ^ 1, kpre, vpre);
      kpre += 64 * DHn;
      vpre += 64;
    }

    const short* Kc = Ks[cur];
    const short* Vc = Vs[cur];

    // ---- S^T = K Q^T : lane holds S[q=c_][key = 16n + 4g_ + i] ----
    f32x4 s[4];
    __builtin_amdgcn_s_setprio(1);
#pragma unroll
    for (int n = 0; n < 4; ++n) {
      f32x4 a = {};
      int key = n * 16 + c_;
#pragma unroll
      for (int kc = 0; kc < 2; ++kc) {
        int slot = (kc * 4 + g_) ^ (key & 7);
        bf16x8 kf = *(const bf16x8*)(Kc + key * 64 + slot * 8);
        a = __builtin_amdgcn_mfma_f32_16x16x32_bf16(kf, qf[kc], a, 0, 0, 0);
      }
      s[n] = a;
    }
    __builtin_amdgcn_s_setprio(0);

    // ---- last-tile index guard (wave-uniform branch; replaces mask) ----
    if (kt == lastt) {
      const int kb = kt * 64 + g_ * 4;
#pragma unroll
      for (int n = 0; n < 4; ++n) {
        const int k0i = kb + n * 16;
        s[n][0] = (k0i + 0 < L) ? s[n][0] : -1e30f;
        s[n][1] = (k0i + 1 < L) ? s[n][1] : -1e30f;
        s[n][2] = (k0i + 2 < L) ? s[n][2] : -1e30f;
        s[n][3] = (k0i + 3 < L) ? s[n][3] : -1e30f;
      }
    }

    // ---- shuffle-free online softmax fast path ----
    float pmax = fmaxf(fmaxf(s[0][0], s[0][1]), fmaxf(s[0][2], s[0][3]));
#pragma unroll
    for (int n = 1; n < 4; ++n)
      pmax = fmaxf(pmax, fmaxf(fmaxf(s[n][0], s[n][1]), fmaxf(s[n][2], s[n][3])));

    if (!__all(pmax - mrun <= 8.f)) {
      // slow path (rare): true cross-lane row max, rescale state
      float pm = fmaxf(pmax, __shfl_xor(pmax, 16));
      pm = fmaxf(pm, __shfl_xor(pm, 32));      // common per q-row
      float mn = fmaxf(mrun, pm);
      float sc = __builtin_amdgcn_exp2f(mrun - mn);
      mrun = mn;
      lrun *= sc;
      float scB[4];
#pragma unroll
      for (int i = 0; i < 4; ++i) scB[i] = __shfl(sc, g_ * 4 + i);
#pragma unroll
      for (int n = 0; n < 4; ++n)
#pragma unroll
        for (int i = 0; i < 4; ++i) o[n][i] *= scB[i];
    }

    // p = exp2(s - mrun), per-lane partial sum; pack via v_cvt_pk_bf16_f32
    float lsum = 0.f;
#pragma unroll
    for (int n = 0; n < 4; ++n) {
      float p0 = __builtin_amdgcn_exp2f(s[n][0] - mrun);
      float p1 = __builtin_amdgcn_exp2f(s[n][1] - mrun);
      float p2 = __builtin_amdgcn_exp2f(s[n][2] - mrun);
      float p3 = __builtin_amdgcn_exp2f(s[n][3] - mrun);
      lsum += (p0 + p1) + (p2 + p3);
      uint2 pk;
      pk.x = cvt_pk_bf16(p0, p1);
      pk.y = cvt_pk_bf16(p2, p3);
      *(uint2*)(PwB + ((c_ * 128) | ((n * 32 + g_ * 8) ^ swz))) = pk;
    }
    lrun += lsum;

    // ---- O += P V ----
    __builtin_amdgcn_s_setprio(1);
#pragma unroll
    for (int ks = 0; ks < 2; ++ks) {
      bf16x8 pf = *(const bf16x8*)(PwB + ((c_ * 128) | ((ks * 64 + g_ * 16) ^ swz)));
#pragma unroll
      for (int n = 0; n < 4; ++n) {
        int d = n * 16 + c_;
        int slot = (ks * 4 + g_) ^ (d & 7);
        bf16x8 vf = *(const bf16x8*)(Vc + d * 64 + slot * 8);
        o[n] = __builtin_amdgcn_mfma_f32_16x16x32_bf16(pf, vf, o[n], 0, 0, 0);
      }
    }
    __builtin_amdgcn_s_setprio(0);

    __syncthreads();   // drains prefetch vmcnt + P lgkm, flips buffers
    cur ^= 1;
  }

  // ---- epilogue: reduce lrun partials once, then out = o / l ----
  lrun += __shfl_xor(lrun, 16);
  lrun += __shfl_xor(lrun, 32);     // now common per q-row
  float lB[4];
#pragma unroll
  for (int i = 0; i < 4; ++i) lB[i] = __shfl(lrun, g_ * 4 + i);
#pragma unroll
  for (int n = 0; n < 4; ++n) {
#pragma unroll
    for (int i = 0; i < 4; ++i) {
      int srow = qt * 128 + w * 16 + g_ * 4 + i;
      int d = n * 16 + c_;
      out[((size_t)b * SQn + srow) * DMn + h * 64 + d] = f2bf(o[n][i] / lB[i]);
    }
  }
#undef STAGE
}

// ---------------- launch ----------------
extern "C" void kernel_launch(void* const* d_in, const int* in_sizes, int n_in,
                              void* d_out, int out_size, void* d_ws, size_t ws_size,
                              hipStream_t stream) {
  const float* Q  = (const float*)d_in[0];
  const float* K  = (const float*)d_in[1];
  const float* V  = (const float*)d_in[2];
  const int* mask = (const int*)d_in[3];
  const float* Wq = (const float*)d_in[4];
  const float* bq = (const float*)d_in[5];
  const float* Wk = (const float*)d_in[6];
  const float* bk = (const float*)d_in[7];
  const float* Wv = (const float*)d_in[8];
  const float* bv = (const float*)d_in[9];
  const float* Wo = (const float*)d_in[10];
  const float* bo = (const float*)d_in[11];

  char* ws = (char*)d_ws;
  const size_t MB = 1024 * 1024;
  short* Qb  = (short*)(ws + 0 * MB);    // 3 x 8MB contiguous (fused cast out)
  short* Wqt = (short*)(ws + 24 * MB);   // 4 x 2MB contiguous (fused transpose out)
  short* Wkt = (short*)(ws + 26 * MB);
  short* Wvt = (short*)(ws + 28 * MB);
  short* Wot = (short*)(ws + 30 * MB);
  short* qp  = (short*)(ws + 32 * MB);   // [B][H][S][64], pre-scaled
  short* kp  = (short*)(ws + 40 * MB);   // [B][H][S_c][64], key-compacted
  short* vpt = (short*)(ws + 48 * MB);   // [B][H][64][S_c]  (V^T, key-compacted)
  int*   posp = (int*)(ws + 56 * MB);    // [B][2048] prefix counts
  int*   Lbp  = (int*)(ws + 56 * MB + 16384);  // [B] valid-key counts
  short* Kb  = Qb + 4 * MB;              // element offsets into fused cast region
  short* Vb  = Qb + 8 * MB;
  short* ao  = Qb;                       // alias: Qb dead after projection GEMM

  const int n4 = (2 * 2048 * 1024) / 4;  // per-tensor float4 count
  cast3_f32_bf16<<<3 * n4 / 256, 256, 0, stream>>>(Q, K, V, Qb, n4);

  transpose_cast4<<<dim3(32, 32, 4), dim3(32, 8), 0, stream>>>(Wq, Wk, Wv, Wo, Wqt);

  mask_scan<<<2, 256, 0, stream>>>(mask, posp, Lbp);

  // fused 3-way projection GEMM (q scaled; k/v key-compacted via partition remap)
  gemm_bt3<<<dim3(32, 8, 3), 256, 0, stream>>>(Qb, Kb, Vb, Wqt, Wkt, Wvt,
                                               bq, bk, bv, qp, kp, vpt,
                                               mask, posp, Lbp);

  attn<<<512, 512, 0, stream>>>(qp, kp, vpt, Lbp, ao);

  // final projection -> f32 output, 128x64 tile = 512 blocks (2/CU)
  gemm_n64<<<dim3(32, 16), 256, 0, stream>>>(ao, Wot, bo, (float*)d_out);
}